// Round 6
// baseline (426.700 us; speedup 1.0000x reference)
//
#include <hip/hip_runtime.h>
#include <hip/hip_bf16.h>

#define NN 100000
#define NE 1600000
#define KF 128     // IN_FEATS
#define CT 256     // NUM_HEADS*OUT_FEATS
#define NH 8

typedef __attribute__((ext_vector_type(8))) short short8;
typedef __attribute__((ext_vector_type(4))) float f32x4;

__device__ __forceinline__ float bf2f(unsigned short u) {
  union { unsigned int i; float f; } x; x.i = ((unsigned int)u) << 16; return x.f;
}
__device__ __forceinline__ unsigned short f2bf(float f) {
  unsigned int b = __float_as_uint(f);
  b += 0x7fffu + ((b >> 16) & 1u);
  return (unsigned short)(b >> 16);
}
__device__ __forceinline__ float lrelu(float e) { return (e > 0.f) ? e : 0.2f * e; }

// ---------------- K0: W (128x256 f32) -> Wt (256x128 bf16, transposed) ----------------
__global__ void k_wconv(const float* __restrict__ W, unsigned short* __restrict__ Wt) {
  int i = blockIdx.x * 256 + threadIdx.x;
  if (i < KF * CT) {
    int k = i >> 8, c = i & 255;
    Wt[c * KF + k] = f2bf(W[i]);
  }
}

// ---------------- K1: ft = feat @ W via bf16 MFMA + el/er epilogue + fused hist ----------------
__global__ __launch_bounds__(256) void k_gemm(
    const float* __restrict__ feat, const unsigned short* __restrict__ Wt,
    const float* __restrict__ attn_l, const float* __restrict__ attn_r,
    unsigned short* __restrict__ ftb, float* __restrict__ el, float* __restrict__ er,
    const int* __restrict__ dst, int* __restrict__ cnt)
{
  __shared__ unsigned short fs[64][136];  // +8 pad: 272B stride -> 2-way alias (free)
  const int tid = threadIdx.x;
  const int lane = tid & 63, w = tid >> 6;
  const int row0 = blockIdx.x * 64;

  for (int i = tid; i < 64 * 32; i += 256) {
    int r = i >> 5, c4 = (i & 31) * 4;
    int gr = row0 + r;
    float4 v = make_float4(0.f, 0.f, 0.f, 0.f);
    if (gr < NN) v = *(const float4*)(feat + (size_t)gr * KF + c4);
    *(ushort4*)(&fs[r][c4]) = make_ushort4(f2bf(v.x), f2bf(v.y), f2bf(v.z), f2bf(v.w));
  }

  const int bc = lane & 15;
  const int bk = (lane >> 4) * 8;
  short8 bfrag[4][4];
#pragma unroll
  for (int ks = 0; ks < 4; ks++)
#pragma unroll
    for (int n = 0; n < 4; n++)
      bfrag[ks][n] = *(const short8*)(Wt + (size_t)(w * 64 + n * 16 + bc) * KF + ks * 32 + bk);

  __syncthreads();

  f32x4 acc[4][4];
#pragma unroll
  for (int m = 0; m < 4; m++)
#pragma unroll
    for (int n = 0; n < 4; n++) acc[m][n] = (f32x4){0.f, 0.f, 0.f, 0.f};

#pragma unroll
  for (int ks = 0; ks < 4; ks++) {
    short8 af[4];
#pragma unroll
    for (int m = 0; m < 4; m++)
      af[m] = *(const short8*)(&fs[m * 16 + bc][ks * 32 + bk]);
#pragma unroll
    for (int m = 0; m < 4; m++)
#pragma unroll
      for (int n = 0; n < 4; n++)
        acc[m][n] = __builtin_amdgcn_mfma_f32_16x16x32_bf16(af[m], bfrag[ks][n], acc[m][n], 0, 0, 0);
  }

  const int rbase = (lane >> 4) * 4;

#pragma unroll
  for (int m = 0; m < 4; m++) {
#pragma unroll
    for (int r = 0; r < 4; r++) {
      int gr = row0 + m * 16 + rbase + r;
      if (gr < NN) {
        unsigned short* op = ftb + (size_t)gr * CT + w * 64 + bc;
#pragma unroll
        for (int n = 0; n < 4; n++) op[n * 16] = f2bf(acc[m][n][r]);
      }
    }
  }

  float al[4], ar[4];
#pragma unroll
  for (int n = 0; n < 4; n++) {
    al[n] = attn_l[w * 64 + n * 16 + bc];
    ar[n] = attn_r[w * 64 + n * 16 + bc];
  }
#pragma unroll
  for (int m = 0; m < 4; m++) {
#pragma unroll
    for (int r = 0; r < 4; r++) {
      float pl0 = acc[m][0][r] * al[0] + acc[m][1][r] * al[1];
      float pl1 = acc[m][2][r] * al[2] + acc[m][3][r] * al[3];
      float pr0 = acc[m][0][r] * ar[0] + acc[m][1][r] * ar[1];
      float pr1 = acc[m][2][r] * ar[2] + acc[m][3][r] * ar[3];
#pragma unroll
      for (int d = 1; d < 16; d <<= 1) {
        pl0 += __shfl_xor(pl0, d);
        pl1 += __shfl_xor(pl1, d);
        pr0 += __shfl_xor(pr0, d);
        pr1 += __shfl_xor(pr1, d);
      }
      if (bc == 0) {
        int gr = row0 + m * 16 + rbase + r;
        if (gr < NN) {
          *(float2*)(el + (size_t)gr * NH + 2 * w) = make_float2(pl0, pl1);
          *(float2*)(er + (size_t)gr * NH + 2 * w) = make_float2(pr0, pr1);
        }
      }
    }
  }

  // fused in-degree histogram
  for (int e = blockIdx.x * 256 + tid; e < NE; e += gridDim.x * 256)
    atomicAdd(&cnt[dst[e]], 1);
}

// ---------------- K4a: per-block sums ----------------
__global__ __launch_bounds__(1024) void k_scan1(const int* __restrict__ cnt, int* __restrict__ bsum) {
  __shared__ int ws[16];
  const int tid = threadIdx.x, lane = tid & 63, wid = tid >> 6;
  int i = blockIdx.x * 1024 + tid;
  int x = (i < NN) ? cnt[i] : 0;
#pragma unroll
  for (int d = 1; d < 64; d <<= 1) x += __shfl_xor(x, d);
  if (lane == 0) ws[wid] = x;
  __syncthreads();
  if (tid == 0) {
    int s = 0;
#pragma unroll
    for (int k = 0; k < 16; k++) s += ws[k];
    bsum[blockIdx.x] = s;
  }
}

// ---------------- K4b: scan block sums ----------------
__global__ void k_scan2(const int* __restrict__ bsum, int* __restrict__ bexc, int nb) {
  __shared__ int wsum[2];
  const int tid = threadIdx.x, lane = tid & 63, wid = tid >> 6;
  int x = (tid < nb) ? bsum[tid] : 0;
  int v = x;
#pragma unroll
  for (int d = 1; d < 64; d <<= 1) { int t = __shfl_up(v, d); if (lane >= d) v += t; }
  if (lane == 63) wsum[wid] = v;
  __syncthreads();
  int pre = (wid > 0) ? wsum[0] : 0;
  if (tid < nb) bexc[tid] = pre + v - x;
}

// ---------------- K4c: apply offsets ----------------
__global__ __launch_bounds__(1024) void k_scan3(const int* __restrict__ cnt, const int* __restrict__ bexc,
                                                int* __restrict__ off, int* __restrict__ cur) {
  __shared__ int ws[16];
  const int tid = threadIdx.x, lane = tid & 63, wid = tid >> 6;
  int i = blockIdx.x * 1024 + tid;
  int x = (i < NN) ? cnt[i] : 0;
  int v = x;
#pragma unroll
  for (int d = 1; d < 64; d <<= 1) { int t = __shfl_up(v, d); if (lane >= d) v += t; }
  if (lane == 63) ws[wid] = v;
  __syncthreads();
  if (tid < 16) {
    int s = ws[tid];
#pragma unroll
    for (int d = 1; d < 16; d <<= 1) { int t = __shfl_up(s, d); if (tid >= d) s += t; }
    ws[tid] = s;
  }
  __syncthreads();
  int pre = bexc[blockIdx.x] + (wid > 0 ? ws[wid - 1] : 0);
  if (i < NN) { int e = pre + v - x; off[i] = e; cur[i] = e; }
  if (blockIdx.x == 0 && tid == 0) off[NN] = NE;
}

// ---------------- K5: scatter src into CSR (4B per edge) ----------------
__global__ void k_scatter(const int* __restrict__ src, const int* __restrict__ dst,
                          int* __restrict__ cur, int* __restrict__ csr_src) {
  int e = blockIdx.x * 256 + threadIdx.x;
  if (e < NE) {
    int sv = src[e];
    int d = dst[e];
    int p = atomicAdd(&cur[d], 1);
    csr_src[p] = sv;
  }
}

// ---------------- K6: per-node aggregation + inv store (no attn writes) ----------------
// 1 wave = 1 node. lane = eg*8 + h for softmax; lane owns cols lane*4..+3 for aggregation.
__global__ __launch_bounds__(256) void k_edge(
    const int* __restrict__ off, const int* __restrict__ csr_src,
    const float* __restrict__ el, const float* __restrict__ er,
    const unsigned short* __restrict__ ftb, const float* __restrict__ bias,
    float* __restrict__ hout, float* __restrict__ inv_out)
{
  const int wid = threadIdx.x >> 6;
  const int lane = threadIdx.x & 63;
  const int n = blockIdx.x * 4 + wid;
  if (n >= NN) return;
  const int beg = off[n], end = off[n + 1];

  if (end == beg) {  // degree 0: output = summed bias / 8
    if (lane < 8) {
      float b0 = 0.f, b1 = 0.f, b2 = 0.f, b3 = 0.f;
#pragma unroll
      for (int hh = 0; hh < NH; hh++) {
        const float* bp = bias + hh * 32 + lane * 4;
        b0 += bp[0]; b1 += bp[1]; b2 += bp[2]; b3 += bp[3];
      }
      float* op = hout + (size_t)n * 32 + lane * 4;
      *(float4*)op = make_float4(b0 * 0.125f, b1 * 0.125f, b2 * 0.125f, b3 * 0.125f);
    }
    return;
  }

  const int h = lane & 7;       // head (softmax layout)
  const int eg = lane >> 3;     // edge-in-group
  const int h_own = lane >> 3;  // head owned in aggregation layout
  const float er_v = er[(size_t)n * NH + h];

  float acc0 = 0.f, acc1 = 0.f, acc2 = 0.f, acc3 = 0.f;
  float wsum = 0.f;   // per-lane partial of head h's denominator (over eg slots)

  for (int g = beg; g < end; g += 8) {
    int s = g + eg;
    bool valid = (s < end);
    int sc = valid ? s : (end - 1);
    int sn = csr_src[sc];
    float e = lrelu(el[(size_t)sn * NH + h] + er_v);
    float wv = valid ? __expf(e) : 0.f;
    wsum += wv;

    ushort4 u[8];
    float av[8];
#pragma unroll
    for (int j = 0; j < 8; j++) {
      av[j] = __shfl(wv, j * 8 + h_own);
      int sj = __shfl(sn, j * 8);
      u[j] = *(const ushort4*)(ftb + (size_t)sj * CT + lane * 4);
    }
#pragma unroll
    for (int j = 0; j < 8; j++) {
      acc0 += bf2f(u[j].x) * av[j];
      acc1 += bf2f(u[j].y) * av[j];
      acc2 += bf2f(u[j].z) * av[j];
      acc3 += bf2f(u[j].w) * av[j];
    }
  }

  // fold denominator over eg (bits 3..5): every lane gets its head's full sum
  wsum += __shfl_xor(wsum, 8); wsum += __shfl_xor(wsum, 16); wsum += __shfl_xor(wsum, 32);
  const float inv = 1.f / wsum;
  if (lane < 8) inv_out[(size_t)n * NH + lane] = inv;  // lane 0..7 holds head 0..7

  const float invh = __shfl(inv, h_own);
  acc0 *= invh; acc1 *= invh; acc2 *= invh; acc3 *= invh;

  // fold heads (lanes differing in bits 3..5 share the same within-head col quad)
#pragma unroll
  for (int mks = 8; mks <= 32; mks <<= 1) {
    acc0 += __shfl_xor(acc0, mks);
    acc1 += __shfl_xor(acc1, mks);
    acc2 += __shfl_xor(acc2, mks);
    acc3 += __shfl_xor(acc3, mks);
  }
  if (lane < 8) {
    float b0 = 0.f, b1 = 0.f, b2 = 0.f, b3 = 0.f;
#pragma unroll
    for (int hh = 0; hh < NH; hh++) {
      const float* bp = bias + hh * 32 + lane * 4;
      b0 += bp[0]; b1 += bp[1]; b2 += bp[2]; b3 += bp[3];
    }
    float* op = hout + (size_t)n * 32 + lane * 4;
    __builtin_nontemporal_store((acc0 + b0) * 0.125f, op + 0);
    __builtin_nontemporal_store((acc1 + b1) * 0.125f, op + 1);
    __builtin_nontemporal_store((acc2 + b2) * 0.125f, op + 2);
    __builtin_nontemporal_store((acc3 + b3) * 0.125f, op + 3);
  }
}

// ---------------- K7: edge-parallel attn (coalesced writes) ----------------
__global__ __launch_bounds__(256) void k_attn(
    const int* __restrict__ src, const int* __restrict__ dst,
    const float* __restrict__ el, const float* __restrict__ er,
    const float* __restrict__ inv, float* __restrict__ attn_out)
{
  int e = blockIdx.x * 256 + threadIdx.x;
  if (e >= NE) return;
  int s = src[e], d = dst[e];
  float4 l0 = *(const float4*)(el + (size_t)s * NH);
  float4 l1 = *(const float4*)(el + (size_t)s * NH + 4);
  float4 r0 = *(const float4*)(er + (size_t)d * NH);
  float4 r1 = *(const float4*)(er + (size_t)d * NH + 4);
  float4 i0 = *(const float4*)(inv + (size_t)d * NH);
  float4 i1 = *(const float4*)(inv + (size_t)d * NH + 4);
  float4 a0, a1;
  a0.x = __expf(lrelu(l0.x + r0.x)) * i0.x;
  a0.y = __expf(lrelu(l0.y + r0.y)) * i0.y;
  a0.z = __expf(lrelu(l0.z + r0.z)) * i0.z;
  a0.w = __expf(lrelu(l0.w + r0.w)) * i0.w;
  a1.x = __expf(lrelu(l1.x + r1.x)) * i1.x;
  a1.y = __expf(lrelu(l1.y + r1.y)) * i1.y;
  a1.z = __expf(lrelu(l1.z + r1.z)) * i1.z;
  a1.w = __expf(lrelu(l1.w + r1.w)) * i1.w;
  float* op = attn_out + (size_t)e * NH;
  __builtin_nontemporal_store(a0.x, op + 0);
  __builtin_nontemporal_store(a0.y, op + 1);
  __builtin_nontemporal_store(a0.z, op + 2);
  __builtin_nontemporal_store(a0.w, op + 3);
  __builtin_nontemporal_store(a1.x, op + 4);
  __builtin_nontemporal_store(a1.y, op + 5);
  __builtin_nontemporal_store(a1.z, op + 6);
  __builtin_nontemporal_store(a1.w, op + 7);
}

extern "C" void kernel_launch(void* const* d_in, const int* in_sizes, int n_in,
                              void* d_out, int out_size, void* d_ws, size_t ws_size,
                              hipStream_t stream) {
  const float* feat   = (const float*)d_in[0];
  const int*   src    = (const int*)d_in[1];
  const int*   dst    = (const int*)d_in[2];
  const float* W      = (const float*)d_in[3];
  const float* attn_l = (const float*)d_in[4];
  const float* attn_r = (const float*)d_in[5];
  const float* bias   = (const float*)d_in[6];

  char* ws = (char*)d_ws;
  size_t o = 0;
  unsigned short* ftb = (unsigned short*)(ws + o); o += (size_t)NN * CT * 2;  // 51.2 MB
  int* csr_src        = (int*)(ws + o);            o += (size_t)NE * 4;       // 6.4 MB
  float* el           = (float*)(ws + o);          o += (size_t)NN * NH * 4;
  float* er           = (float*)(ws + o);          o += (size_t)NN * NH * 4;
  float* inv          = (float*)(ws + o);          o += (size_t)NN * NH * 4;
  int* cnt            = (int*)(ws + o);            o += (size_t)NN * 4;
  int* off            = (int*)(ws + o);            o += (size_t)(NN + 2) * 4;
  int* cur            = (int*)(ws + o);            o += (size_t)NN * 4;
  unsigned short* Wt  = (unsigned short*)(ws + o); o += (size_t)CT * KF * 2;
  int* bsum           = (int*)(ws + o);            o += 128 * 4;
  int* bexc           = (int*)(ws + o);            o += 128 * 4;

  float* hout     = (float*)d_out;                 // NN*32
  float* attn_out = hout + (size_t)NN * 32;        // NE*8

  const int NB = (NN + 1023) / 1024;  // 98
  const int GB = (NN + 63) / 64;      // 1563

  hipMemsetAsync(cnt, 0, NN * sizeof(int), stream);
  k_wconv<<<(KF * CT + 255) / 256, 256, 0, stream>>>(W, Wt);
  k_gemm<<<GB, 256, 0, stream>>>(feat, Wt, attn_l, attn_r, ftb, el, er, dst, cnt);
  k_scan1<<<NB, 1024, 0, stream>>>(cnt, bsum);
  k_scan2<<<1, 128, 0, stream>>>(bsum, bexc, NB);
  k_scan3<<<NB, 1024, 0, stream>>>(cnt, bexc, off, cur);
  k_scatter<<<(NE + 255) / 256, 256, 0, stream>>>(src, dst, cur, csr_src);
  k_edge<<<(NN + 3) / 4, 256, 0, stream>>>(off, csr_src, el, er, ftb, bias, hout, inv);
  k_attn<<<(NE + 255) / 256, 256, 0, stream>>>(src, dst, el, er, inv, attn_out);
}